// Round 14
// baseline (75.544 us; speedup 1.0000x reference)
//
#include <hip/hip_runtime.h>

// Barrier-free, LDS-free scanline Laplacian-pyramid level, depth-2 pipeline.
// Wave = 128-px strip x sh rows; lane owns col pair. 9-row rolling register
// window (w0..w6 + 2 prefetched) so TWO row-pair loads are always in flight
// (Little's-law: 2KB/wave x 24 waves/CU = 48KB/CU outstanding). All cross-
// lane exchange via __shfl; no LDS, no barriers. refl() keeps every load
// in-image, so tail prefetches are valid cache hits -> no guard branch.

__device__ __forceinline__ int refl(int t, int n) {
    if (t < 0) t = -t;
    if (t >= n) t = 2 * (n - 1) - t;
    return t;
}

__global__ __launch_bounds__(256, 6) void lap_scan_kernel(
    const float* __restrict__ cur, float* __restrict__ lap,
    float* __restrict__ down, int H, int W, int sh)
{
    const int wid = threadIdx.x >> 6, lane = threadIdx.x & 63;
    const int x0 = blockIdx.x * 128;
    const int y0 = (blockIdx.y * 4 + wid) * sh;
    const int img = blockIdx.z;
    const int Hh = H >> 1, Wh = W >> 1;

    const float* curb = cur + (size_t)img * H * W;
    float* lapb = lap + (size_t)img * H * W;
    float* downb = down + (size_t)img * Hh * Wh;

    const int c0 = x0 + 2 * lane;                       // own col pair (in-image)
    const bool haloLane = (lane < 2) | (lane >= 62);
    // halo pairs: lane0:(x0-4,-3) lane1:(x0-2,-1) lane62:(x0+128,129) lane63:(x0+130,131)
    const int hc0 = (lane < 2) ? (x0 - 4 + 2 * lane) : (x0 + 4 + 2 * lane);
    const bool xb = (x0 == 0) || (x0 + 128 == W);
    const int hg0 = refl(hc0, W), hg1 = refl(hc0 + 1, W);

    auto loadOwn = [&](int rho) -> float2 {
        return *(const float2*)(curb + (size_t)refl(y0 + rho, H) * W + c0);
    };
    auto loadHalo = [&](int rho) -> float2 {
        const float* rp = curb + (size_t)refl(y0 + rho, H) * W;
        float2 v;
        if (xb) { v.x = rp[hg0]; v.y = rp[hg1]; }
        else    { v = *(const float2*)(rp + hc0); }
        return v;
    };

    // prologue: window = pixel rows y0-4 .. y0+2 (iter a uses rows 2a-2..2a+2)
    float2 w0 = loadOwn(-4), w1 = loadOwn(-3), w2 = loadOwn(-2),
           w3 = loadOwn(-1), w4 = loadOwn(0),  w5 = loadOwn(1),
           w6 = loadOwn(2);
    float2 h0 = {0,0}, h1 = {0,0}, h2 = {0,0}, h3 = {0,0}, h4 = {0,0},
           h5 = {0,0}, h6 = {0,0};
    if (haloLane) {
        h0 = loadHalo(-4); h1 = loadHalo(-3); h2 = loadHalo(-2);
        h3 = loadHalo(-1); h4 = loadHalo(0);  h5 = loadHalo(1);
        h6 = loadHalo(2);
    }

    float dm2a = 0, dm2b = 0, dm2c = 0, dm1a = 0, dm1b = 0, dm1c = 0;
    const int aEnd = sh >> 1;

    for (int a = -1; a <= aEnd; ++a) {
        // 1. issue loads two row-pairs ahead (rows 2a+5, 2a+6); always valid
        //    via refl; they drain under this iteration's + next's math
        float2 nw5 = loadOwn(2 * a + 5), nw6 = loadOwn(2 * a + 6);
        float2 nh5 = {0,0}, nh6 = {0,0};
        if (haloLane) { nh5 = loadHalo(2 * a + 5); nh6 = loadHalo(2 * a + 6); }

        // 2. vertical 5-tap (own + halo cols) on rows 2a-2..2a+2
        float vE = w0.x + 4.f * w1.x + 6.f * w2.x + 4.f * w3.x + w4.x;
        float vO = w0.y + 4.f * w1.y + 6.f * w2.y + 4.f * w3.y + w4.y;
        float hE = h0.x + 4.f * h1.x + 6.f * h2.x + 4.f * h3.x + h4.x;
        float hO = h0.y + 4.f * h1.y + 6.f * h2.y + 4.f * h3.y + h4.y;

        // 3. route halo/edge values (all-lane uniform broadcasts)
        float bhE0 = __shfl(hE, 0),  bhO0 = __shfl(hO, 0);
        float bhE1 = __shfl(hE, 1),  bhO1 = __shfl(hO, 1);
        float bhE62 = __shfl(hE, 62), bhO62 = __shfl(hO, 62);
        float bhE63 = __shfl(hE, 63);
        float bvE0 = __shfl(vE, 0);
        float bvE63 = __shfl(vE, 63), bvO63 = __shfl(vO, 63);

        float sE = __shfl_up(vE, 1), sO = __shfl_up(vO, 1);
        float nE = __shfl_down(vE, 1);
        float eL = (lane == 0) ? bhE1 : sE;    // t(c0-2)
        float oL = (lane == 0) ? bhO1 : sO;    // t(c0-1)
        float eR = (lane == 63) ? bhE62 : nE;  // t(c0+2)

        // 4. horizontal 5-tap -> down value at down col x0/2+lane (row y0/2+a)
        float dv = (eL + 4.f * oL + 6.f * vE + 4.f * vO + eR) * (1.f / 256.f);
        float dvm1 = (bhE0 + 4.f * bhO0 + 6.f * bhE1 + 4.f * bhO1 + bvE0) * (1.f / 256.f);
        float dvp64 = (bvE63 + 4.f * bvO63 + 6.f * bhE62 + 4.f * bhO62 + bhE63) * (1.f / 256.f);

        // 5. neighbor triplet (down cols lane-1, lane, lane+1)
        float su = __shfl_up(dv, 1), sd = __shfl_down(dv, 1);
        float da = (lane == 0) ? dvm1 : su;
        float db = dv;
        float dc = (lane == 63) ? dvp64 : sd;

        if (a >= 0 && a < aEnd)
            downb[(size_t)((y0 >> 1) + a) * Wh + (x0 >> 1) + lane] = dv;

        // 6. emit lap rows y0+2a-2 (=w0) and y0+2a-1 (=w1)
        if (a >= 1) {
            float CEa = dm2a + 6.f * dm1a + da;
            float CEb = dm2b + 6.f * dm1b + db;
            float CEc = dm2c + 6.f * dm1c + dc;
            float COa = 4.f * (dm1a + da);
            float COb = 4.f * (dm1b + db);
            float COc = 4.f * (dm1c + dc);
            float2 oe, oo;
            oe.x = w0.x - (CEa + 6.f * CEb + CEc) * (1.f / 64.f);
            oe.y = w0.y - 4.f * (CEb + CEc) * (1.f / 64.f);
            oo.x = w1.x - (COa + 6.f * COb + COc) * (1.f / 64.f);
            oo.y = w1.y - 4.f * (COb + COc) * (1.f / 64.f);
            *(float2*)(lapb + (size_t)(y0 + 2 * a - 2) * W + c0) = oe;
            *(float2*)(lapb + (size_t)(y0 + 2 * a - 1) * W + c0) = oo;
        }

        // 7. shift rolling state by one row-pair
        dm2a = dm1a; dm2b = dm1b; dm2c = dm1c;
        dm1a = da;   dm1b = db;   dm1c = dc;
        w0 = w2; w1 = w3; w2 = w4; w3 = w5; w4 = w6; w5 = nw5; w6 = nw6;
        h0 = h2; h1 = h3; h2 = h4; h3 = h5; h4 = h6; h5 = nh5; h6 = nh6;
    }
}

extern "C" void kernel_launch(void* const* d_in, const int* in_sizes, int n_in,
                              void* d_out, int out_size, void* d_ws, size_t ws_size,
                              hipStream_t stream) {
    const float* img = (const float*)d_in[0];
    float* out = (float*)d_out;

    const long long BC = 8LL * 3;
    const long long n0 = BC * 1024 * 1024;
    const long long n1 = BC * 512 * 512;
    const long long n2 = BC * 256 * 256;

    float* out0 = out;            // lap0
    float* out1 = out0 + n0;      // lap1
    float* out2 = out1 + n1;      // lap2
    float* out3 = out2 + n2;      // down2

    float* ws0 = (float*)d_ws;    // down0
    float* ws1 = ws0 + n1;        // down1

    // grid: (W/128 strips, H/(4*sh) wave-quads, 24 images)
    lap_scan_kernel<<<dim3(1024 / 128, 1024 / (4 * 32), (int)BC), 256, 0, stream>>>(
        img, out0, ws0, 1024, 1024, 32);
    lap_scan_kernel<<<dim3(512 / 128, 512 / (4 * 16), (int)BC), 256, 0, stream>>>(
        ws0, out1, ws1, 512, 512, 16);
    lap_scan_kernel<<<dim3(256 / 128, 256 / (4 * 8), (int)BC), 256, 0, stream>>>(
        ws1, out2, out3, 256, 256, 8);
}